// Round 10
// baseline (1088.272 us; speedup 1.0000x reference)
//
#include <hip/hip_runtime.h>

// 2-layer LSTM (B=4096, T=512, H=50) + FC head.
// R10 vs R9 (684/777 us, VALUBusy 69%, trans-pipe ~= half the busy cycles):
//  (1) 1024-thr block, 16 waves (8 L0 + 8 L1, 2 tiles each) -> 4 waves/SIMD
//      latency hiding (was 2). Reg audit: L1 path ~116 <= 128 budget.
//  (2) 4-way paired reciprocal in the gate finish: 1 rcp + 9 mul replaces
//      4 rcp (trans ops are ~quarter-rate). Preacts clamped to [-20, +10]
//      so the 4-product stays < 2^116 (no inf poisoning).
//  (3) bias + x*Wih0 folded into the MFMA C-initializer (8 fewer VALU/tile).
//  (4) single unified t-loop; barriers OUTSIDE the L0/L1 divergence.
// Math otherwise identical to R9 (bf16 hi/lo, 3 mfma/product) -> absmax ~0.

typedef __attribute__((ext_vector_type(8))) short short8;
typedef __attribute__((ext_vector_type(4))) float f32x4;

#define LOG2E 1.44269504088896340736f

__device__ __forceinline__ unsigned short bf16_rne(float f) {
  unsigned int u = __float_as_uint(f);
  u += 0x7FFFu + ((u >> 16) & 1u);
  return (unsigned short)(u >> 16);
}
__device__ __forceinline__ float bf16f(unsigned short h) {
  return __uint_as_float(((unsigned int)h) << 16);
}
template <int CTRL>
__device__ __forceinline__ float dppf(float v) {
  return __int_as_float(
      __builtin_amdgcn_mov_dpp(__float_as_int(v), CTRL, 0xf, 0xf, true));
}
__device__ __forceinline__ float rcp_(float x) { return __builtin_amdgcn_rcpf(x); }
__device__ __forceinline__ float exp2_(float x) { return __builtin_amdgcn_exp2f(x); }
__device__ __forceinline__ f32x4 mfma16(short8 a, short8 b, f32x4 c) {
  return __builtin_amdgcn_mfma_f32_16x16x32_bf16(a, b, c, 0, 0, 0);
}

union ABu { struct { uint2 a, b; } u; short8 v; };
__device__ __forceinline__ short8 rdfrag(const unsigned short* p0,
                                         const unsigned short* p1) {
  ABu t;
  t.u.a = *(const uint2*)p0;
  t.u.b = *(const uint2*)p1;
  return t.v;
}

// B-fragment (hi & lo) of W (50x50 logical, gate-major rows) for column
// (n,gate); k = kbase + 16*(e>>2) + 4*lg + (e&3).
__device__ __forceinline__ void loadB(const float* __restrict__ W, int n,
                                      int gate, int kbase, int lg,
                                      short8& h8, short8& l8) {
#pragma unroll
  for (int e = 0; e < 8; ++e) {
    const int k = kbase + 16 * (e >> 2) + 4 * lg + (e & 3);
    const bool v = (n < 50) && (k < 50);
    const float w = v ? W[(gate * 50 + n) * 50 + k] : 0.f;
    const unsigned short hb = bf16_rne(w);
    const unsigned short lb = bf16_rne(w - bf16f(hb));
    h8[e] = (short)hb;
    l8[e] = (short)lb;
  }
}

// 4x4 quad transpose over (gate-lane q) x (acc index): 8 dpp + 8 cndmask.
#define TRSP(r0, r1, r2, r3)                                   \
  {                                                            \
    const float t0 = dppf<0xB1>(r1), t1 = dppf<0xB1>(r0);      \
    const float t2 = dppf<0xB1>(r3), t3 = dppf<0xB1>(r2);      \
    r0 = o1 ? t0 : r0; r1 = o1 ? r1 : t1;                      \
    r2 = o1 ? t2 : r2; r3 = o1 ? r3 : t3;                      \
    const float s0 = dppf<0x4E>(r2), s1 = dppf<0x4E>(r3);      \
    const float s2 = dppf<0x4E>(r0), s3 = dppf<0x4E>(r1);      \
    r0 = o2 ? s0 : r0; r1 = o2 ? s1 : r1;                      \
    r2 = o2 ? r2 : s2; r3 = o2 ? r3 : s3;                      \
  }

// Gate finish: TRSP -> clamp -> 4x exp2 -> paired rcp -> c,h -> bf16 write.
// After TRSP: p0..p3 = {i,f,g,o} preacts of batch bown for this tile's unit.
#define FIN(ACC, cvar, woffv, PH, PL, WPc)                               \
  {                                                                      \
    float p0 = ACC[0], p1 = ACC[1], p2 = ACC[2], p3 = ACC[3];            \
    TRSP(p0, p1, p2, p3)                                                 \
    p0 = fmaxf(p0, -20.f); p1 = fmaxf(p1, -20.f);                        \
    p3 = fmaxf(p3, -20.f); p2 = fminf(p2, 10.f);                         \
    const float e0 = exp2_(-LOG2E * p0), e1 = exp2_(-LOG2E * p1);        \
    const float e2 = exp2_(2.f * LOG2E * p2), e3 = exp2_(-LOG2E * p3);   \
    const float r0 = 1.f + e0, r1 = 1.f + e1;                            \
    const float r2 = 1.f + e2, r3 = 1.f + e3;                            \
    const float P01 = r0 * r1, P23 = r2 * r3;                            \
    const float R = rcp_(P01 * P23);                                     \
    const float R01 = R * P23, R23 = R * P01;                            \
    const float i_ = R01 * r1, f_ = R01 * r0;                            \
    const float g2 = R23 * r3, o_ = R23 * r2;                            \
    const float g_ = 1.f - 2.f * g2;                                     \
    const float c = f_ * cvar + i_ * g_;                                 \
    cvar = c;                                                            \
    const float ec = exp2_(2.f * LOG2E * c);                             \
    const float qc = rcp_(1.f + ec);                                     \
    const float th = 1.f - 2.f * qc;                                     \
    const float h = o_ * th;                                             \
    const unsigned short hh = bf16_rne(h);                               \
    const unsigned short hl = bf16_rne(h - bf16f(hh));                   \
    PH[WPc][woffv] = hh;                                                 \
    PL[WPc][woffv] = hl;                                                 \
  }

__global__ __launch_bounds__(1024) void lstm2_kernel(
    const float* __restrict__ x,
    const float* __restrict__ Wih0, const float* __restrict__ Whh0,
    const float* __restrict__ bih0, const float* __restrict__ bhh0,
    const float* __restrict__ Wih1, const float* __restrict__ Whh1,
    const float* __restrict__ bih1, const float* __restrict__ bhh1,
    const float* __restrict__ fcW, const float* __restrict__ fcb,
    float* __restrict__ out) {
  const int tid = threadIdx.x;
  const int lane = tid & 63;
  const int wv = tid >> 6;       // wave 0..15
  const bool isL1 = wv >= 8;     // waves 8-15: layer 1 (lagged one step)
  const int wt = (wv & 7) * 2;   // first of this wave's two N-tiles
  const int lg = lane >> 4;      // 0..3 (k-slice / batch-group)
  const int l15 = lane & 15;
  const int q = lane & 3;        // gate column of this lane
  const int m = l15 >> 2;        // unit-sub within tile
  const int bbase = blockIdx.x * 16;

  // h planes: [parity][kt*512 + hh*256 + s*64 + b*4 + e] ushort,
  // where unit u = kt*32 + hh*16 + s*4 + e. A-frag read = 8*lane + const.
  __shared__ unsigned short H0h[2][1024], H0l[2][1024];
  __shared__ unsigned short H1h[2][1024], H1l[2][1024];
  __shared__ float xs2[64][16];    // x chunk: [t within chunk][batch]
  __shared__ float ldspad[15616];  // 61 KB pin -> ~83 KB total -> 1 blk/CU

  ((volatile float*)ldspad)[tid] = 0.f;
  {  // zero all planes, both parities (1024 uints each, 1024 threads)
    ((unsigned int*)H0h)[tid] = 0u; ((unsigned int*)H0l)[tid] = 0u;
    ((unsigned int*)H1h)[tid] = 0u; ((unsigned int*)H1l)[tid] = 0u;
  }

  const int lane4 = lane * 4;    // ushort index of this lane's A-frag slot
  const bool o1 = (q & 1) != 0, o2 = (q & 2) != 0;
  const int bown = 4 * lg + q;   // batch owned after transpose

#define WOFF(u) (((u) >> 5 << 9) + ((((u) >> 4) & 1) << 8) + \
                 ((((u) >> 2) & 3) << 6) + (bown << 2) + ((u) & 3))

  // ---- per-role weights (loaded conditionally; dead on the other path) ----
  short8 W0h0_A, W0l0_A, W0h1_A, W0l1_A;       // L0 tile A (Whh0)
  short8 W0h0_B, W0l0_B, W0h1_B, W0l1_B;       // L0 tile B
  short8 WIh0_A, WIl0_A, WIh1_A, WIl1_A;       // L1 tile A (Wih1)
  short8 WHh0_A, WHl0_A, WHh1_A, WHl1_A;       // L1 tile A (Whh1)
  short8 WIh0_B, WIl0_B, WIh1_B, WIl1_B;       // L1 tile B
  short8 WHh0_B, WHl0_B, WHh1_B, WHl1_B;       // L1 tile B
  float bias_A = 0.f, bias_B = 0.f, wx_A = 0.f, wx_B = 0.f;
  float cA = 0.f, cB = 0.f;                    // cell state (owned batch)
  int woffA, woffB;

  const int uA = 4 * wt + m, uB = 4 * (wt + 1) + m;
  woffA = WOFF(uA);
  woffB = WOFF(uB);
  if (!isL1) {
    loadB(Whh0, uA, q, 0, lg, W0h0_A, W0l0_A);
    loadB(Whh0, uA, q, 32, lg, W0h1_A, W0l1_A);
    loadB(Whh0, uB, q, 0, lg, W0h0_B, W0l0_B);
    loadB(Whh0, uB, q, 32, lg, W0h1_B, W0l1_B);
    if (uA < 50) {
      bias_A = bih0[q * 50 + uA] + bhh0[q * 50 + uA];
      wx_A = Wih0[q * 50 + uA];
    }
    if (uB < 50) {
      bias_B = bih0[q * 50 + uB] + bhh0[q * 50 + uB];
      wx_B = Wih0[q * 50 + uB];
    }
  } else {
    loadB(Wih1, uA, q, 0, lg, WIh0_A, WIl0_A);
    loadB(Wih1, uA, q, 32, lg, WIh1_A, WIl1_A);
    loadB(Whh1, uA, q, 0, lg, WHh0_A, WHl0_A);
    loadB(Whh1, uA, q, 32, lg, WHh1_A, WHl1_A);
    loadB(Wih1, uB, q, 0, lg, WIh0_B, WIl0_B);
    loadB(Wih1, uB, q, 32, lg, WIh1_B, WIl1_B);
    loadB(Whh1, uB, q, 0, lg, WHh0_B, WHl0_B);
    loadB(Whh1, uB, q, 32, lg, WHh1_B, WHl1_B);
    if (uA < 50) bias_A = bih1[q * 50 + uA] + bhh1[q * 50 + uA];
    if (uB < 50) bias_B = bih1[q * 50 + uB] + bhh1[q * 50 + uB];
  }

#define STAGE(ch)                                                         \
  if (tid < 256) {                                                        \
    const int b_ = tid >> 4, fg_ = tid & 15;                              \
    const float4 v_ = *(const float4*)&x[(size_t)(bbase + b_) * 512 +     \
                                         (ch) * 64 + 4 * fg_];            \
    xs2[4 * fg_ + 0][b_] = v_.x; xs2[4 * fg_ + 1][b_] = v_.y;             \
    xs2[4 * fg_ + 2][b_] = v_.z; xs2[4 * fg_ + 3][b_] = v_.w;             \
  }

  // L0 step s: read h0[s-1] (parity RP=(s+1)&1), write h0[s] (WP=s&1).
#define L0STEP(RP, WP, tmv)                                                    \
  {                                                                            \
    const short8 ah0 = rdfrag(&H0h[RP][lane4], &H0h[RP][lane4 + 256]);         \
    const short8 al0 = rdfrag(&H0l[RP][lane4], &H0l[RP][lane4 + 256]);         \
    const short8 ah1 = rdfrag(&H0h[RP][512 + lane4], &H0h[RP][768 + lane4]);   \
    const short8 al1 = rdfrag(&H0l[RP][512 + lane4], &H0l[RP][768 + lane4]);   \
    const float4 xv = *(const float4*)&xs2[tmv][4 * lg];                       \
    {                                                                          \
      f32x4 acc = {fmaf(xv.x, wx_A, bias_A), fmaf(xv.y, wx_A, bias_A),         \
                   fmaf(xv.z, wx_A, bias_A), fmaf(xv.w, wx_A, bias_A)};        \
      acc = mfma16(al0, W0h0_A, acc);                                          \
      acc = mfma16(ah0, W0l0_A, acc);                                          \
      acc = mfma16(ah0, W0h0_A, acc);                                          \
      acc = mfma16(al1, W0h1_A, acc);                                          \
      acc = mfma16(ah1, W0l1_A, acc);                                          \
      acc = mfma16(ah1, W0h1_A, acc);                                          \
      FIN(acc, cA, woffA, H0h, H0l, WP)                                        \
    }                                                                          \
    {                                                                          \
      f32x4 acc = {fmaf(xv.x, wx_B, bias_B), fmaf(xv.y, wx_B, bias_B),         \
                   fmaf(xv.z, wx_B, bias_B), fmaf(xv.w, wx_B, bias_B)};        \
      acc = mfma16(al0, W0h0_B, acc);                                          \
      acc = mfma16(ah0, W0l0_B, acc);                                          \
      acc = mfma16(ah0, W0h0_B, acc);                                          \
      acc = mfma16(al1, W0h1_B, acc);                                          \
      acc = mfma16(ah1, W0l1_B, acc);                                          \
      acc = mfma16(ah1, W0h1_B, acc);                                          \
      FIN(acc, cB, woffB, H0h, H0l, WP)                                        \
    }                                                                          \
  }

  // L1 step s: read h0[s] (parity P0=s&1), h1[s-1] (R1=(s+1)&1), write
  // h1[s] (W1=s&1). Phase-scoped frags keep register peak low.
#define L1STEP(P0, R1, W1)                                                     \
  {                                                                            \
    f32x4 accA = {bias_A, bias_A, bias_A, bias_A};                             \
    f32x4 accB = {bias_B, bias_B, bias_B, bias_B};                             \
    {                                                                          \
      const short8 bh0 = rdfrag(&H0h[P0][lane4], &H0h[P0][lane4 + 256]);       \
      const short8 bl0 = rdfrag(&H0l[P0][lane4], &H0l[P0][lane4 + 256]);       \
      const short8 bh1 = rdfrag(&H0h[P0][512 + lane4], &H0h[P0][768 + lane4]); \
      const short8 bl1 = rdfrag(&H0l[P0][512 + lane4], &H0l[P0][768 + lane4]); \
      accA = mfma16(bl0, WIh0_A, accA);                                        \
      accA = mfma16(bh0, WIl0_A, accA);                                        \
      accA = mfma16(bh0, WIh0_A, accA);                                        \
      accA = mfma16(bl1, WIh1_A, accA);                                        \
      accA = mfma16(bh1, WIl1_A, accA);                                        \
      accA = mfma16(bh1, WIh1_A, accA);                                        \
      accB = mfma16(bl0, WIh0_B, accB);                                        \
      accB = mfma16(bh0, WIl0_B, accB);                                        \
      accB = mfma16(bh0, WIh0_B, accB);                                        \
      accB = mfma16(bl1, WIh1_B, accB);                                        \
      accB = mfma16(bh1, WIl1_B, accB);                                        \
      accB = mfma16(bh1, WIh1_B, accB);                                        \
    }                                                                          \
    {                                                                          \
      const short8 ch0 = rdfrag(&H1h[R1][lane4], &H1h[R1][lane4 + 256]);       \
      const short8 cl0 = rdfrag(&H1l[R1][lane4], &H1l[R1][lane4 + 256]);       \
      const short8 ch1 = rdfrag(&H1h[R1][512 + lane4], &H1h[R1][768 + lane4]); \
      const short8 cl1 = rdfrag(&H1l[R1][512 + lane4], &H1l[R1][768 + lane4]); \
      accA = mfma16(cl0, WHh0_A, accA);                                        \
      accA = mfma16(ch0, WHl0_A, accA);                                        \
      accA = mfma16(ch0, WHh0_A, accA);                                        \
      accA = mfma16(cl1, WHh1_A, accA);                                        \
      accA = mfma16(ch1, WHl1_A, accA);                                        \
      accA = mfma16(ch1, WHh1_A, accA);                                        \
      accB = mfma16(cl0, WHh0_B, accB);                                        \
      accB = mfma16(ch0, WHl0_B, accB);                                        \
      accB = mfma16(ch0, WHh0_B, accB);                                        \
      accB = mfma16(cl1, WHh1_B, accB);                                        \
      accB = mfma16(ch1, WHl1_B, accB);                                        \
      accB = mfma16(ch1, WHh1_B, accB);                                        \
    }                                                                          \
    FIN(accA, cA, woffA, H1h, H1l, W1)                                         \
    FIN(accB, cB, woffB, H1h, H1l, W1)                                         \
  }

  STAGE(0)
  __syncthreads();

  for (int it = 0; it < 256; ++it) {
    const int te = 2 * it, to = te + 1;
    // even step te: L0 computes h0[te]; L1 computes h1[te-1] (skip te=0)
    if (!isL1) {
      L0STEP(1, 0, (te & 63))
    } else if (te > 0) {
      L1STEP(1, 0, 1)
    }
    __syncthreads();
    // odd step to: L0 computes h0[to]; L1 computes h1[to-1]
    if (!isL1) {
      L0STEP(0, 1, (to & 63))
    } else {
      L1STEP(0, 1, 0)
    }
    __syncthreads();
    if ((to & 63) == 63 && to != 511) {
      STAGE((to >> 6) + 1)
      __syncthreads();
    }
  }
  // epilogue: h1[511] (s=511: P0=1, R1=0, W1=1)
  if (isL1) {
    L1STEP(1, 0, 1)
  }
  __syncthreads();

  // ---- FC head: out[b] = fc_b + sum_j fcW[j] * h1[511][b][j] ----
  if (tid < 16) {
    float s = fcb[0];
    for (int j = 0; j < 50; ++j) {
      const int idx = ((j >> 5) << 9) + (((j >> 4) & 1) << 8) +
                      (((j >> 2) & 3) << 6) + (tid << 2) + (j & 3);
      s += fcW[j] * (bf16f(H1h[1][idx]) + bf16f(H1l[1][idx]));
    }
    out[bbase + tid] = s;
  }
}

extern "C" void kernel_launch(void* const* d_in, const int* in_sizes, int n_in,
                              void* d_out, int out_size, void* d_ws, size_t ws_size,
                              hipStream_t stream) {
  const float* x    = (const float*)d_in[0];
  const float* Wih0 = (const float*)d_in[1];
  const float* Whh0 = (const float*)d_in[2];
  const float* bih0 = (const float*)d_in[3];
  const float* bhh0 = (const float*)d_in[4];
  const float* Wih1 = (const float*)d_in[5];
  const float* Whh1 = (const float*)d_in[6];
  const float* bih1 = (const float*)d_in[7];
  const float* bhh1 = (const float*)d_in[8];
  const float* fcW  = (const float*)d_in[9];
  const float* fcb  = (const float*)d_in[10];
  float* out = (float*)d_out;

  const int B = out_size;          // 4096
  const int blocks = B / 16;       // 256
  lstm2_kernel<<<dim3(blocks), dim3(1024), 0, stream>>>(
      x, Wih0, Whh0, bih0, bhh0, Wih1, Whh1, bih1, bhh1, fcW, fcb, out);
}

// Round 11
// 717.148 us; speedup vs baseline: 1.5175x; 1.5175x over previous
//
#include <hip/hip_runtime.h>

// 2-layer LSTM (B=4096, T=512, H=50) + FC head.
// R11 = R9's proven skeleton (512 thr, 8 waves: 4 L0 + 4 L1, 4 tiles/wave,
// 2 waves/SIMD, VGPR 124 no-spill, 1 barrier/step) + R10's numerically
// validated FIN math only:
//  - paired reciprocal: 1 rcp serves all 4 gates (7 trans/cell, was 10);
//    preacts clamped (sigm args >= -20, tanh arg <= +10) so the 4-product
//    stays finite. R10 measured absmax 4.88e-4 <= 1.63e-3 with this math.
//  - bias + x*Wih0 folded into the MFMA C-initializer.
// R10's 16-wave variant REGRESSED (allocator self-capped VGPR=64, spilled
// 43MB): wave-count changes are off the table; this keeps R9's shape.

typedef __attribute__((ext_vector_type(8))) short short8;
typedef __attribute__((ext_vector_type(4))) float f32x4;

#define LOG2E 1.44269504088896340736f

__device__ __forceinline__ unsigned short bf16_rne(float f) {
  unsigned int u = __float_as_uint(f);
  u += 0x7FFFu + ((u >> 16) & 1u);
  return (unsigned short)(u >> 16);
}
__device__ __forceinline__ float bf16f(unsigned short h) {
  return __uint_as_float(((unsigned int)h) << 16);
}
template <int CTRL>
__device__ __forceinline__ float dppf(float v) {
  return __int_as_float(
      __builtin_amdgcn_mov_dpp(__float_as_int(v), CTRL, 0xf, 0xf, true));
}
__device__ __forceinline__ float rcp_(float x) { return __builtin_amdgcn_rcpf(x); }
__device__ __forceinline__ float exp2_(float x) { return __builtin_amdgcn_exp2f(x); }
__device__ __forceinline__ f32x4 mfma16(short8 a, short8 b, f32x4 c) {
  return __builtin_amdgcn_mfma_f32_16x16x32_bf16(a, b, c, 0, 0, 0);
}

union ABu { struct { uint2 a, b; } u; short8 v; };
__device__ __forceinline__ short8 rdfrag(const unsigned short* p0,
                                         const unsigned short* p1) {
  ABu t;
  t.u.a = *(const uint2*)p0;
  t.u.b = *(const uint2*)p1;
  return t.v;
}

// B-fragment (hi & lo) of W (50x50 logical, gate-major rows) for column
// (n,gate); k = kbase + 16*(e>>2) + 4*lg + (e&3).
__device__ __forceinline__ void loadB(const float* __restrict__ W, int n,
                                      int gate, int kbase, int lg,
                                      short8& h8, short8& l8) {
#pragma unroll
  for (int e = 0; e < 8; ++e) {
    const int k = kbase + 16 * (e >> 2) + 4 * lg + (e & 3);
    const bool v = (n < 50) && (k < 50);
    const float w = v ? W[(gate * 50 + n) * 50 + k] : 0.f;
    const unsigned short hb = bf16_rne(w);
    const unsigned short lb = bf16_rne(w - bf16f(hb));
    h8[e] = (short)hb;
    l8[e] = (short)lb;
  }
}

#define TILES(X) X(0) X(1) X(2) X(3)

// 4x4 quad transpose over (gate-lane q) x (acc index): 8 dpp + 8 cndmask.
#define TRSP(r0, r1, r2, r3)                                   \
  {                                                            \
    const float t0 = dppf<0xB1>(r1), t1 = dppf<0xB1>(r0);      \
    const float t2 = dppf<0xB1>(r3), t3 = dppf<0xB1>(r2);      \
    r0 = o1 ? t0 : r0; r1 = o1 ? r1 : t1;                      \
    r2 = o1 ? t2 : r2; r3 = o1 ? r3 : t3;                      \
    const float s0 = dppf<0x4E>(r2), s1 = dppf<0x4E>(r3);      \
    const float s2 = dppf<0x4E>(r0), s3 = dppf<0x4E>(r1);      \
    r0 = o2 ? s0 : r0; r1 = o2 ? s1 : r1;                      \
    r2 = o2 ? r2 : s2; r3 = o2 ? r3 : s3;                      \
  }

// Gate finish: TRSP -> clamp -> 4 exp2 -> ONE rcp (paired) -> c,h -> bf16.
// After TRSP: p0..p3 = {i,f,g,o} preacts of batch bown for this unit.
#define FIN(ACC, cvar, woffv, PH, PL, WPc)                               \
  {                                                                      \
    float p0 = ACC[0], p1 = ACC[1], p2 = ACC[2], p3 = ACC[3];            \
    TRSP(p0, p1, p2, p3)                                                 \
    p0 = fmaxf(p0, -20.f); p1 = fmaxf(p1, -20.f);                        \
    p3 = fmaxf(p3, -20.f); p2 = fminf(p2, 10.f);                         \
    const float e0 = exp2_(-LOG2E * p0), e1 = exp2_(-LOG2E * p1);        \
    const float e2 = exp2_(2.f * LOG2E * p2), e3 = exp2_(-LOG2E * p3);   \
    const float r0 = 1.f + e0, r1 = 1.f + e1;                            \
    const float r2 = 1.f + e2, r3 = 1.f + e3;                            \
    const float P01 = r0 * r1, P23 = r2 * r3;                            \
    const float R = rcp_(P01 * P23);                                     \
    const float R01 = R * P23, R23 = R * P01;                            \
    const float i_ = R01 * r1, f_ = R01 * r0;                            \
    const float g2 = R23 * r3, o_ = R23 * r2;                            \
    const float g_ = 1.f - 2.f * g2;                                     \
    const float c = f_ * cvar + i_ * g_;                                 \
    cvar = c;                                                            \
    const float ec = exp2_(2.f * LOG2E * c);                             \
    const float qc = rcp_(1.f + ec);                                     \
    const float th = 1.f - 2.f * qc;                                     \
    const float h = o_ * th;                                             \
    const unsigned short hh = bf16_rne(h);                               \
    const unsigned short hl = bf16_rne(h - bf16f(hh));                   \
    PH[WPc][woffv] = hh;                                                 \
    PL[WPc][woffv] = hl;                                                 \
  }

__global__ __launch_bounds__(512) void lstm2_kernel(
    const float* __restrict__ x,
    const float* __restrict__ Wih0, const float* __restrict__ Whh0,
    const float* __restrict__ bih0, const float* __restrict__ bhh0,
    const float* __restrict__ Wih1, const float* __restrict__ Whh1,
    const float* __restrict__ bih1, const float* __restrict__ bhh1,
    const float* __restrict__ fcW, const float* __restrict__ fcb,
    float* __restrict__ out) {
  const int tid = threadIdx.x;
  const int lane = tid & 63;
  const int wv = tid >> 6;      // wave 0..7
  const int wg = wv & 3;        // group index within layer-group
  const bool isL1 = wv >= 4;    // waves 4-7: layer 1
  const int lg = lane >> 4;     // 0..3 (k-slice / batch-group)
  const int l15 = lane & 15;
  const int q = lane & 3;       // gate column of this lane
  const int m = l15 >> 2;       // unit-sub within tile
  const int bbase = blockIdx.x * 16;

  // h planes: [parity][kt*512 + hh*256 + s*64 + b*4 + e] ushort,
  // where unit u = kt*32 + hh*16 + s*4 + e. A-frag read = 8*lane + const.
  __shared__ unsigned short H0h[2][1024], H0l[2][1024];
  __shared__ unsigned short H1h[2][1024], H1l[2][1024];
  __shared__ float xs2[64][16];    // x chunk: [t within chunk][batch]
  __shared__ float ldspad[16000];  // 62.5 KB pin -> 82.5 KB total, 1 blk/CU

  ((volatile float*)ldspad)[tid] = 0.f;

  for (int i = tid; i < 1024; i += 512) {  // zero all planes, both parities
    ((unsigned int*)H0h)[i] = 0u; ((unsigned int*)H0l)[i] = 0u;
    ((unsigned int*)H1h)[i] = 0u; ((unsigned int*)H1l)[i] = 0u;
  }

  const int lane4 = lane * 4;  // ushort index of this lane's A-frag slot
  const bool o1 = (q & 1) != 0, o2 = (q & 2) != 0;
  const int bown = 4 * lg + q;  // batch owned after transpose

#define WOFF(u) (((u) >> 5 << 9) + ((((u) >> 4) & 1) << 8) + \
                 ((((u) >> 2) & 3) << 6) + (bown << 2) + ((u) & 3))

#define STAGE(c)                                                        \
  {                                                                     \
    const int b_ = tid >> 4, fg_ = tid & 15;                            \
    const float4 v_ = *(const float4*)&x[(size_t)(bbase + b_) * 512 +   \
                                         (c) * 64 + 4 * fg_];           \
    xs2[4 * fg_ + 0][b_] = v_.x; xs2[4 * fg_ + 1][b_] = v_.y;           \
    xs2[4 * fg_ + 2][b_] = v_.z; xs2[4 * fg_ + 3][b_] = v_.w;           \
  }

  if (!isL1) {
    // ================= LAYER-0 WAVES =================
#define DECL0(T) short8 W0h0_##T, W0l0_##T, W0h1_##T, W0l1_##T;  \
    float bias0_##T, wx_##T; float c0_##T = 0.f; int woff_##T;
    TILES(DECL0)
#define LOAD0(T)                                                     \
    { const int u = 16 * wg + 4 * T + m;                             \
      loadB(Whh0, u, q, 0, lg, W0h0_##T, W0l0_##T);                  \
      loadB(Whh0, u, q, 32, lg, W0h1_##T, W0l1_##T);                 \
      const bool v = u < 50;                                         \
      bias0_##T = v ? (bih0[q * 50 + u] + bhh0[q * 50 + u]) : 0.f;   \
      wx_##T = v ? Wih0[q * 50 + u] : 0.f;                           \
      woff_##T = WOFF(u); }
    TILES(LOAD0)

#define L0TILE(T, WP)                                                \
    { f32x4 acc = {fmaf(xv.x, wx_##T, bias0_##T),                    \
                   fmaf(xv.y, wx_##T, bias0_##T),                    \
                   fmaf(xv.z, wx_##T, bias0_##T),                    \
                   fmaf(xv.w, wx_##T, bias0_##T)};                   \
      acc = mfma16(al0, W0h0_##T, acc);                              \
      acc = mfma16(ah0, W0l0_##T, acc);                              \
      acc = mfma16(ah0, W0h0_##T, acc);                              \
      acc = mfma16(al1, W0h1_##T, acc);                              \
      acc = mfma16(ah1, W0l1_##T, acc);                              \
      acc = mfma16(ah1, W0h1_##T, acc);                              \
      FIN(acc, c0_##T, woff_##T, H0h, H0l, WP) }

#define L0STEP(RP, WP, tm)                                           \
    { const short8 ah0 = rdfrag(&H0h[RP][lane4], &H0h[RP][lane4 + 256]); \
      const short8 al0 = rdfrag(&H0l[RP][lane4], &H0l[RP][lane4 + 256]); \
      const short8 ah1 = rdfrag(&H0h[RP][512 + lane4], &H0h[RP][768 + lane4]); \
      const short8 al1 = rdfrag(&H0l[RP][512 + lane4], &H0l[RP][768 + lane4]); \
      const float4 xv = *(const float4*)&xs2[tm][4 * lg];            \
      L0TILE(0, WP) L0TILE(1, WP) L0TILE(2, WP) L0TILE(3, WP) }

    STAGE(0) __syncthreads();
    L0STEP(1, 0, 0) __syncthreads();  // tt=0: read zeros(parity1), write p0
    for (int it = 0; it < 255; ++it) {
      const int todd = 2 * it + 1;
      L0STEP(0, 1, (todd & 63)) __syncthreads();
      const int tev = todd + 1;
      if ((tev & 63) == 0) { STAGE(tev >> 6) __syncthreads(); }
      L0STEP(1, 0, (tev & 63)) __syncthreads();
    }
    L0STEP(0, 1, 63) __syncthreads();  // tt=511
    __syncthreads();                   // matches L1 epilogue barrier
  } else {
    // ================= LAYER-1 WAVES =================
#define DECL1(T) short8 WIh0_##T, WIl0_##T, WIh1_##T, WIl1_##T,      \
    WHh0_##T, WHl0_##T, WHh1_##T, WHl1_##T;                          \
    float bias1_##T; float c1_##T = 0.f; int woff_##T;
    TILES(DECL1)
#define LOAD1(T)                                                     \
    { const int u = 16 * wg + 4 * T + m;                             \
      loadB(Wih1, u, q, 0, lg, WIh0_##T, WIl0_##T);                  \
      loadB(Wih1, u, q, 32, lg, WIh1_##T, WIl1_##T);                 \
      loadB(Whh1, u, q, 0, lg, WHh0_##T, WHl0_##T);                  \
      loadB(Whh1, u, q, 32, lg, WHh1_##T, WHl1_##T);                 \
      const bool v = u < 50;                                         \
      bias1_##T = v ? (bih1[q * 50 + u] + bhh1[q * 50 + u]) : 0.f;   \
      woff_##T = WOFF(u); }
    TILES(LOAD1)

#define L1TILE(T, W1)                                                \
    { f32x4 acc = {bias1_##T, bias1_##T, bias1_##T, bias1_##T};      \
      acc = mfma16(bl0, WIh0_##T, acc);                              \
      acc = mfma16(bh0, WIl0_##T, acc);                              \
      acc = mfma16(bh0, WIh0_##T, acc);                              \
      acc = mfma16(bl1, WIh1_##T, acc);                              \
      acc = mfma16(bh1, WIl1_##T, acc);                              \
      acc = mfma16(bh1, WIh1_##T, acc);                              \
      acc = mfma16(cl0, WHh0_##T, acc);                              \
      acc = mfma16(ch0, WHl0_##T, acc);                              \
      acc = mfma16(ch0, WHh0_##T, acc);                              \
      acc = mfma16(cl1, WHh1_##T, acc);                              \
      acc = mfma16(ch1, WHl1_##T, acc);                              \
      acc = mfma16(ch1, WHh1_##T, acc);                              \
      FIN(acc, c1_##T, woff_##T, H1h, H1l, W1) }

#define L1STEP(P0, R1, W1)                                               \
    { const short8 bh0 = rdfrag(&H0h[P0][lane4], &H0h[P0][lane4 + 256]); \
      const short8 bl0 = rdfrag(&H0l[P0][lane4], &H0l[P0][lane4 + 256]); \
      const short8 bh1 = rdfrag(&H0h[P0][512 + lane4], &H0h[P0][768 + lane4]); \
      const short8 bl1 = rdfrag(&H0l[P0][512 + lane4], &H0l[P0][768 + lane4]); \
      const short8 ch0 = rdfrag(&H1h[R1][lane4], &H1h[R1][lane4 + 256]); \
      const short8 cl0 = rdfrag(&H1l[R1][lane4], &H1l[R1][lane4 + 256]); \
      const short8 ch1 = rdfrag(&H1h[R1][512 + lane4], &H1h[R1][768 + lane4]); \
      const short8 cl1 = rdfrag(&H1l[R1][512 + lane4], &H1l[R1][768 + lane4]); \
      L1TILE(0, W1) L1TILE(1, W1) L1TILE(2, W1) L1TILE(3, W1) }

    __syncthreads(); __syncthreads();  // mirror peel barriers (no compute, tt=0 skip)
    for (int it = 0; it < 255; ++it) {
      // tt odd: h0[tt-1]=p0, h1[tt-2]=p1, write h1[tt-1]=p0
      L1STEP(0, 1, 0) __syncthreads();
      if (((2 * it + 2) & 63) == 0) __syncthreads();  // mirror stage barrier
      // tt even: h0[tt-1]=p1, h1[tt-2]=p0, write h1[tt-1]=p1
      L1STEP(1, 0, 1) __syncthreads();
    }
    L1STEP(0, 1, 0) __syncthreads();  // tt=511 -> h1[510]
    L1STEP(1, 0, 1) __syncthreads();  // epilogue -> h1[511] (parity 1)
  }

  // ---- FC head: out[b] = fc_b + sum_j fcW[j] * h1[511][b][j] ----
  if (tid < 16) {
    float s = fcb[0];
    for (int j = 0; j < 50; ++j) {
      const int idx = ((j >> 5) << 9) + (((j >> 4) & 1) << 8) +
                      (((j >> 2) & 3) << 6) + (tid << 2) + (j & 3);
      s += fcW[j] * (bf16f(H1h[1][idx]) + bf16f(H1l[1][idx]));
    }
    out[bbase + tid] = s;
  }
}

extern "C" void kernel_launch(void* const* d_in, const int* in_sizes, int n_in,
                              void* d_out, int out_size, void* d_ws, size_t ws_size,
                              hipStream_t stream) {
  const float* x    = (const float*)d_in[0];
  const float* Wih0 = (const float*)d_in[1];
  const float* Whh0 = (const float*)d_in[2];
  const float* bih0 = (const float*)d_in[3];
  const float* bhh0 = (const float*)d_in[4];
  const float* Wih1 = (const float*)d_in[5];
  const float* Whh1 = (const float*)d_in[6];
  const float* bih1 = (const float*)d_in[7];
  const float* bhh1 = (const float*)d_in[8];
  const float* fcW  = (const float*)d_in[9];
  const float* fcb  = (const float*)d_in[10];
  float* out = (float*)d_out;

  const int B = out_size;          // 4096
  const int blocks = B / 16;       // 256
  lstm2_kernel<<<dim3(blocks), dim3(512), 0, stream>>>(
      x, Wih0, Whh0, bih0, bhh0, Wih1, Whh1, bih1, bhh1, fcW, fcb, out);
}

// Round 12
// 480.028 us; speedup vs baseline: 2.2671x; 1.4940x over previous
//
#include <hip/hip_runtime.h>

// 2-layer LSTM (B=4096, T=512, H=50) + FC head.
// R12 vs R11 (814 us steady, latency-bound: wall 3816 cyc/SIMD/step vs
// ~1300 est. issue):
//  (1) GATE-MAJOR tiles: wave wg owns units 16wg..+15; its 4 tiles = the 4
//      gates. Lane ends with i,f,g,o of (unit l15, 4 batches) in its own
//      4 accumulators -> TRSP + selects DELETED from the critical path.
//  (2) f16 everywhere: h = single f16 plane (|h|<=1, err 2^-11); W = f16
//      hi/lo pair -> 2 MFMA/product (was 3 bf16), half the A-frag reads,
//      half the h pack/writes. c stays fp32 in registers.
//  (3) paired-rcp REVERTED (R11 evidence: serial chain beat its op saving;
//      4 independent rcps pipeline better). bias/x stay folded in C-init.
//  (4) skeleton (8 waves: 4 L0 + 4 L1, barrier mirroring, parities, LDS
//      pin, staging) copied from R11 verbatim -- proven correct.
// Weights land in AGPRs (R11 evidence: MFMA reads B from AGPR free);
// VALU-visible regs ~75 -> safe under any allocator cap.

typedef __attribute__((ext_vector_type(8))) _Float16 half8;
typedef __attribute__((ext_vector_type(4))) float f32x4;

#define LOG2E 1.44269504088896340736f

__device__ __forceinline__ float rcp_(float x) { return __builtin_amdgcn_rcpf(x); }
__device__ __forceinline__ float exp2_(float x) { return __builtin_amdgcn_exp2f(x); }
__device__ __forceinline__ float sigm(float x) {
  return rcp_(1.f + exp2_(-LOG2E * x));
}
__device__ __forceinline__ float tanh_(float x) {
  return 1.f - 2.f * rcp_(1.f + exp2_(2.f * LOG2E * x));
}
__device__ __forceinline__ f32x4 mfma16(half8 a, half8 b, f32x4 c) {
  return __builtin_amdgcn_mfma_f32_16x16x32_f16(a, b, c, 0, 0, 0);
}

union ABu { struct { uint2 a, b; } u; half8 v; };
__device__ __forceinline__ half8 rdfrag(const _Float16* p0, const _Float16* p1) {
  ABu t;
  t.u.a = *(const uint2*)p0;
  t.u.b = *(const uint2*)p1;
  return t.v;
}

// B-fragment (f16 hi + lo) of W (50x50 logical) for output column (n,gate);
// k = kbase + 16*(e>>2) + 4*lg + (e&3).
__device__ __forceinline__ void loadW(const float* __restrict__ W, int n,
                                      int gate, int kbase, int lg,
                                      half8& h8, half8& l8) {
#pragma unroll
  for (int e = 0; e < 8; ++e) {
    const int k = kbase + 16 * (e >> 2) + 4 * lg + (e & 3);
    const bool v = (n < 50) && (k < 50);
    const float w = v ? W[(gate * 50 + n) * 50 + k] : 0.f;
    const _Float16 hi = (_Float16)w;
    h8[e] = hi;
    l8[e] = (_Float16)(w - (float)hi);
  }
}

#define GATES(X) X(0) X(1) X(2) X(3)

__global__ __launch_bounds__(512) void lstm2_kernel(
    const float* __restrict__ x,
    const float* __restrict__ Wih0, const float* __restrict__ Whh0,
    const float* __restrict__ bih0, const float* __restrict__ bhh0,
    const float* __restrict__ Wih1, const float* __restrict__ Whh1,
    const float* __restrict__ bih1, const float* __restrict__ bhh1,
    const float* __restrict__ fcW, const float* __restrict__ fcb,
    float* __restrict__ out) {
  const int tid = threadIdx.x;
  const int lane = tid & 63;
  const int wv = tid >> 6;      // wave 0..7
  const int wg = wv & 3;        // unit-group within layer role
  const bool isL1 = wv >= 4;    // waves 4-7: layer 1 (lagged one step)
  const int lg = lane >> 4;     // 0..3 (k-slice / batch-group)
  const int l15 = lane & 15;
  const int bbase = blockIdx.x * 16;

  // h planes (f16): [parity][idx], idx(u,b) = (u>>5)*512 + ((u>>4)&1)*256 +
  // ((u>>2)&3)*64 + b*4 + (u&3). A-frag read = two b64 at 8*lane (+256/512/768).
  __shared__ _Float16 H0[2][1024], H1[2][1024];
  __shared__ float xs2[64][16];    // x chunk: [t within chunk][batch]
  __shared__ float ldspad[18688];  // 74.75 KB pin -> ~87 KB total, 1 blk/CU

  ((volatile float*)ldspad)[tid] = 0.f;

  for (int i = tid; i < 1024; i += 512) {  // zero both parities of both planes
    ((unsigned int*)H0)[i] = 0u;
    ((unsigned int*)H1)[i] = 0u;
  }

  const int lane4 = lane * 4;   // f16 index of this lane's A-frag slot
  const int u = 16 * wg + l15;  // this lane's output unit
  const bool uv = (u < 50);
  // write base for (u, batches 4lg..4lg+3): +4 per batch row
  const int woff = ((u >> 5) << 9) + (((u >> 4) & 1) << 8) +
                   (((u >> 2) & 3) << 6) + ((4 * lg) << 2) + (u & 3);

#define STAGE(c)                                                        \
  {                                                                     \
    const int b_ = tid >> 4, fg_ = tid & 15;                            \
    const float4 v_ = *(const float4*)&x[(size_t)(bbase + b_) * 512 +   \
                                         (c) * 64 + 4 * fg_];           \
    xs2[4 * fg_ + 0][b_] = v_.x; xs2[4 * fg_ + 1][b_] = v_.y;           \
    xs2[4 * fg_ + 2][b_] = v_.z; xs2[4 * fg_ + 3][b_] = v_.w;           \
  }

  if (!isL1) {
    // ================= LAYER-0 WAVES (tid < 256) =================
#define DECL0(G) half8 W0h_##G, W0l_##G, W1h_##G, W1l_##G;  \
    float bi_##G = 0.f, wx_##G = 0.f;
    GATES(DECL0)
#define LOAD0(G)                                              \
    { loadW(Whh0, u, G, 0, lg, W0h_##G, W0l_##G);             \
      loadW(Whh0, u, G, 32, lg, W1h_##G, W1l_##G);            \
      if (uv) {                                               \
        bi_##G = bih0[G * 50 + u] + bhh0[G * 50 + u];         \
        wx_##G = Wih0[G * 50 + u];                            \
      } }
    GATES(LOAD0)
    float cc0 = 0.f, cc1 = 0.f, cc2 = 0.f, cc3 = 0.f;

#define MM0(G, ACC)                                           \
    ACC = mfma16(f0, W0h_##G, ACC);                           \
    ACC = mfma16(f0, W0l_##G, ACC);                           \
    ACC = mfma16(f1, W1h_##G, ACC);                           \
    ACC = mfma16(f1, W1l_##G, ACC);
#define FIN0(r, WP)                                           \
    { const float i_ = sigm(ai[r]), ff = sigm(af[r]);         \
      const float g_ = tanh_(ag[r]), o_ = sigm(ao[r]);        \
      cc##r = ff * cc##r + i_ * g_;                           \
      H0[WP][woff + 4 * (r)] = (_Float16)(o_ * tanh_(cc##r)); }

#define L0STEP(RP, WP, tm)                                                  \
    { const half8 f0 = rdfrag(&H0[RP][lane4], &H0[RP][lane4 + 256]);        \
      const half8 f1 = rdfrag(&H0[RP][512 + lane4], &H0[RP][768 + lane4]);  \
      const float4 xv = *(const float4*)&xs2[tm][4 * lg];                   \
      f32x4 ai = {fmaf(xv.x, wx_0, bi_0), fmaf(xv.y, wx_0, bi_0),           \
                  fmaf(xv.z, wx_0, bi_0), fmaf(xv.w, wx_0, bi_0)};          \
      f32x4 af = {fmaf(xv.x, wx_1, bi_1), fmaf(xv.y, wx_1, bi_1),           \
                  fmaf(xv.z, wx_1, bi_1), fmaf(xv.w, wx_1, bi_1)};          \
      f32x4 ag = {fmaf(xv.x, wx_2, bi_2), fmaf(xv.y, wx_2, bi_2),           \
                  fmaf(xv.z, wx_2, bi_2), fmaf(xv.w, wx_2, bi_2)};          \
      f32x4 ao = {fmaf(xv.x, wx_3, bi_3), fmaf(xv.y, wx_3, bi_3),           \
                  fmaf(xv.z, wx_3, bi_3), fmaf(xv.w, wx_3, bi_3)};          \
      MM0(0, ai) MM0(1, af) MM0(2, ag) MM0(3, ao)                           \
      FIN0(0, WP) FIN0(1, WP) FIN0(2, WP) FIN0(3, WP) }

    STAGE(0) __syncthreads();
    L0STEP(1, 0, 0) __syncthreads();  // tt=0: read zeros(parity1), write p0
    for (int it = 0; it < 255; ++it) {
      const int todd = 2 * it + 1;
      L0STEP(0, 1, (todd & 63)) __syncthreads();
      const int tev = todd + 1;
      if ((tev & 63) == 0) { STAGE(tev >> 6) __syncthreads(); }
      L0STEP(1, 0, (tev & 63)) __syncthreads();
    }
    L0STEP(0, 1, 63) __syncthreads();  // tt=511
    __syncthreads();                   // matches L1 epilogue barrier
  } else {
    // ================= LAYER-1 WAVES =================
#define DECL1(G) half8 I0h_##G, I0l_##G, I1h_##G, I1l_##G,    \
        R0h_##G, R0l_##G, R1h_##G, R1l_##G;                   \
    float bi_##G = 0.f;
    GATES(DECL1)
#define LOAD1(G)                                              \
    { loadW(Wih1, u, G, 0, lg, I0h_##G, I0l_##G);             \
      loadW(Wih1, u, G, 32, lg, I1h_##G, I1l_##G);            \
      loadW(Whh1, u, G, 0, lg, R0h_##G, R0l_##G);             \
      loadW(Whh1, u, G, 32, lg, R1h_##G, R1l_##G);            \
      if (uv) bi_##G = bih1[G * 50 + u] + bhh1[G * 50 + u]; }
    GATES(LOAD1)
    float cc0 = 0.f, cc1 = 0.f, cc2 = 0.f, cc3 = 0.f;

#define MM1(G, ACC)                                           \
    ACC = mfma16(f0, I0h_##G, ACC);                           \
    ACC = mfma16(f0, I0l_##G, ACC);                           \
    ACC = mfma16(f1, I1h_##G, ACC);                           \
    ACC = mfma16(f1, I1l_##G, ACC);                           \
    ACC = mfma16(g0, R0h_##G, ACC);                           \
    ACC = mfma16(g0, R0l_##G, ACC);                           \
    ACC = mfma16(g1, R1h_##G, ACC);                           \
    ACC = mfma16(g1, R1l_##G, ACC);
#define FIN1(r, W1)                                           \
    { const float i_ = sigm(ai[r]), ff = sigm(af[r]);         \
      const float g_ = tanh_(ag[r]), o_ = sigm(ao[r]);        \
      cc##r = ff * cc##r + i_ * g_;                           \
      H1[W1][woff + 4 * (r)] = (_Float16)(o_ * tanh_(cc##r)); }

#define L1STEP(P0, R1, W1)                                                  \
    { const half8 f0 = rdfrag(&H0[P0][lane4], &H0[P0][lane4 + 256]);        \
      const half8 f1 = rdfrag(&H0[P0][512 + lane4], &H0[P0][768 + lane4]);  \
      const half8 g0 = rdfrag(&H1[R1][lane4], &H1[R1][lane4 + 256]);        \
      const half8 g1 = rdfrag(&H1[R1][512 + lane4], &H1[R1][768 + lane4]);  \
      f32x4 ai = {bi_0, bi_0, bi_0, bi_0};                                  \
      f32x4 af = {bi_1, bi_1, bi_1, bi_1};                                  \
      f32x4 ag = {bi_2, bi_2, bi_2, bi_2};                                  \
      f32x4 ao = {bi_3, bi_3, bi_3, bi_3};                                  \
      MM1(0, ai) MM1(1, af) MM1(2, ag) MM1(3, ao)                           \
      FIN1(0, W1) FIN1(1, W1) FIN1(2, W1) FIN1(3, W1) }

    __syncthreads(); __syncthreads();  // mirror peel barriers (tt=0 skip)
    for (int it = 0; it < 255; ++it) {
      // tt odd: h0[tt-1]=p0, h1[tt-2]=p1, write h1[tt-1]=p0
      L1STEP(0, 1, 0) __syncthreads();
      if (((2 * it + 2) & 63) == 0) __syncthreads();  // mirror stage barrier
      // tt even: h0[tt-1]=p1, h1[tt-2]=p0, write h1[tt-1]=p1
      L1STEP(1, 0, 1) __syncthreads();
    }
    L1STEP(0, 1, 0) __syncthreads();  // tt=511 -> h1[510]
    L1STEP(1, 0, 1) __syncthreads();  // epilogue -> h1[511] (parity 1)
  }

  // ---- FC head: out[b] = fc_b + sum_j fcW[j] * h1[511][b][j] ----
  if (tid < 16) {
    float s = fcb[0];
    for (int j = 0; j < 50; ++j) {
      const int idx = ((j >> 5) << 9) + (((j >> 4) & 1) << 8) +
                      (((j >> 2) & 3) << 6) + (tid << 2) + (j & 3);
      s += fcW[j] * (float)H1[1][idx];
    }
    out[bbase + tid] = s;
  }
}

extern "C" void kernel_launch(void* const* d_in, const int* in_sizes, int n_in,
                              void* d_out, int out_size, void* d_ws, size_t ws_size,
                              hipStream_t stream) {
  const float* x    = (const float*)d_in[0];
  const float* Wih0 = (const float*)d_in[1];
  const float* Whh0 = (const float*)d_in[2];
  const float* bih0 = (const float*)d_in[3];
  const float* bhh0 = (const float*)d_in[4];
  const float* Wih1 = (const float*)d_in[5];
  const float* Whh1 = (const float*)d_in[6];
  const float* bih1 = (const float*)d_in[7];
  const float* bhh1 = (const float*)d_in[8];
  const float* fcW  = (const float*)d_in[9];
  const float* fcb  = (const float*)d_in[10];
  float* out = (float*)d_out;

  const int B = out_size;          // 4096
  const int blocks = B / 16;       // 256
  lstm2_kernel<<<dim3(blocks), dim3(512), 0, stream>>>(
      x, Wih0, Whh0, bih0, bhh0, Wih1, Whh1, bih1, bhh1, fcW, fcb, out);
}